// Round 3
// baseline (604.732 us; speedup 1.0000x reference)
//
#include <hip/hip_runtime.h>

#define NFEAT 256
#define GS 32
#define NG 8
#define BATCH 32
#define HW 4096
#define NTOT (BATCH*HW)   // 131072 samples per channel
#define EPSV 1e-5f

// ws layout (float offsets)
#define RPART_SZ (NG*64*1024)                 // 524288 floats
#define SPART_OFF (RPART_SZ)                  // 8*64*32 = 16384
#define WMT_OFF   (SPART_OFF + NG*64*32)      // 8*1024
#define BETA_OFF  (WMT_OFF + NG*1024)         // 8*32

// 16 FMAs/sample-quad on a 4x4 tile + channel-sum accumulation
#define GRAM_STEP(RA, CB) do {                                   \
    _Pragma("unroll")                                            \
    for (int i_ = 0; i_ < 4; ++i_) {                             \
        _Pragma("unroll")                                        \
        for (int j_ = 0; j_ < 4; ++j_) {                         \
            float a_ = acc[i_][j_];                              \
            a_ = fmaf(RA[i_].x, CB[j_].x, a_);                   \
            a_ = fmaf(RA[i_].y, CB[j_].y, a_);                   \
            a_ = fmaf(RA[i_].z, CB[j_].z, a_);                   \
            a_ = fmaf(RA[i_].w, CB[j_].w, a_);                   \
            acc[i_][j_] = a_;                                    \
        }                                                        \
        srow[i_] += (RA[i_].x + RA[i_].y) + (RA[i_].z + RA[i_].w); \
    }                                                            \
} while (0)

// ---------------------------------------------------------------------------
// Kernel 1: per-(g,b,half) partial raw gram R = X X^T and channel sums S.
// R3 post-mortem: dur was IDENTICAL (169us) at 22% and 44% occupancy with
// VALUBusy pinned at 20.8% -> latency-serialized per iteration. VGPR_Count=52
// shows the compiler never prefetched (needs +64 regs) despite the 128 cap:
// every iter = 8 loads -> vmcnt(0) -> 64 FMA, stall on the critical path of
// every wave. R4: EXPLICIT register double-buffer (named bufs, no runtime
// indexing). Preload iters 0,1; body computes buf0, prefetches it+2,
// computes buf1, prefetches it+3. ~1 compute phase of lookahead per load.
// ---------------------------------------------------------------------------
__global__ __launch_bounds__(1024, 4) void dbn_stats(const float* __restrict__ x,
                                                     float* __restrict__ Rpart,
                                                     float* __restrict__ Spart) {
    int bx = blockIdx.x;            // 0..511
    int g  = bx >> 6;
    int pb = bx & 63;               // b*2 + h
    int b  = pb >> 1, h = pb & 1;
    int tid = threadIdx.x;
    int w  = tid >> 6;              // wave 0..15 (sample-split: 128 each)
    int t  = tid & 63;
    int tr = t >> 3, tc = t & 7;    // 8x8 tile grid; tile = 4 rows x 4 cols

    const float* xg = x + ((size_t)(b*NFEAT + g*GS))*HW + h*2048 + w*128;
    const float* rp0 = xg + (size_t)(tr*4)*HW;
    const float* cp0 = xg + (size_t)(tc*4)*HW;

    float acc[4][4];
    float srow[4];
    #pragma unroll
    for (int i = 0; i < 4; ++i) {
        srow[i] = 0.f;
        #pragma unroll
        for (int j = 0; j < 4; ++j) acc[i][j] = 0.f;
    }

    float4 ra0[4], cb0[4], ra1[4], cb1[4];
    #pragma unroll
    for (int i = 0; i < 4; ++i) ra0[i] = *(const float4*)(rp0 + (size_t)i*HW + 0);
    #pragma unroll
    for (int j = 0; j < 4; ++j) cb0[j] = *(const float4*)(cp0 + (size_t)j*HW + 0);
    #pragma unroll
    for (int i = 0; i < 4; ++i) ra1[i] = *(const float4*)(rp0 + (size_t)i*HW + 4);
    #pragma unroll
    for (int j = 0; j < 4; ++j) cb1[j] = *(const float4*)(cp0 + (size_t)j*HW + 4);

    // iters 0..31; body handles (it, it+1), prefetches (it+2, it+3).
    // Last body at it=28 prefetches 30,31 (in-range); epilogue computes them.
    #pragma unroll 1
    for (int it = 0; it < 30; it += 2) {
        GRAM_STEP(ra0, cb0);
        #pragma unroll
        for (int i = 0; i < 4; ++i) ra0[i] = *(const float4*)(rp0 + (size_t)i*HW + (it+2)*4);
        #pragma unroll
        for (int j = 0; j < 4; ++j) cb0[j] = *(const float4*)(cp0 + (size_t)j*HW + (it+2)*4);
        GRAM_STEP(ra1, cb1);
        #pragma unroll
        for (int i = 0; i < 4; ++i) ra1[i] = *(const float4*)(rp0 + (size_t)i*HW + (it+3)*4);
        #pragma unroll
        for (int j = 0; j < 4; ++j) cb1[j] = *(const float4*)(cp0 + (size_t)j*HW + (it+3)*4);
    }
    GRAM_STEP(ra0, cb0);   // it = 30
    GRAM_STEP(ra1, cb1);   // it = 31

    // cross-wave reduction via LDS (epilogue, once per block).
    __shared__ float red[16][64][17];   // ~69.6 KB, odd stride = conflict-free
    __shared__ float sred[16][8][4];    // 2 KB
    #pragma unroll
    for (int i = 0; i < 4; ++i)
        #pragma unroll
        for (int j = 0; j < 4; ++j)
            red[w][t][i*4 + j] = acc[i][j];
    if (tc == 0) {
        #pragma unroll
        for (int i = 0; i < 4; ++i) sred[w][tr][i] = srow[i];
    }
    __syncthreads();

    // 1024 threads <-> 1024 gram entries: 16 LDS reads + 1 coalesced store.
    float* Rp = Rpart + (size_t)(g*64 + pb)*1024;
    {
        int c = tid >> 5, d = tid & 31;
        int tile = (c >> 2)*8 + (d >> 2);
        int slot = (c & 3)*4 + (d & 3);
        float s = 0.f;
        #pragma unroll
        for (int ww = 0; ww < 16; ++ww) s += red[ww][tile][slot];
        Rp[tid] = s;
    }
    if (tid < 32) {
        int c = tid;
        float s = 0.f;
        #pragma unroll
        for (int ww = 0; ww < 16; ++ww) s += sred[ww][c>>2][c&3];
        Spart[(size_t)(g*64 + pb)*32 + c] = s;
    }
}

// ---------------------------------------------------------------------------
// Kernel 2: per-group solver.
// R4: the tid<32 Spart reduce was a 64-deep CHAINED dependent-load loop at
// cross-XCD latency (~25us serial while 992 threads waited). Now 512 threads
// x 4 partials + LDS tree. Rpart reduce: fully unrolled, 4 independent
// accumulators -> all 64 loads in flight, one latency exposure.
// ---------------------------------------------------------------------------
__global__ __launch_bounds__(1024) void dbn_solver(const float* __restrict__ Rpart, const float* __restrict__ Spart,
                           const float* __restrict__ weight, const float* __restrict__ bias,
                           float* __restrict__ wmT, float* __restrict__ beta) {
    __shared__ float Y[1024], Z[1024], T[1024], S[32], M[32], Spr[16][32];
    __shared__ float sh_s;
    int g = blockIdx.x;
    int tid = threadIdx.x;
    int c = tid >> 5, d = tid & 31;

    if (tid < 512) {
        int ch = tid & 31, p = tid >> 5;      // p = 0..15
        float s = 0.f;
        #pragma unroll
        for (int q = 0; q < 4; ++q)
            s += Spart[(size_t)(g*64 + p*4 + q)*32 + ch];
        Spr[p][ch] = s;
    }
    float r0 = 0.f, r1 = 0.f, r2 = 0.f, r3 = 0.f;
    #pragma unroll
    for (int pb = 0; pb < 64; pb += 4) {
        r0 += Rpart[(size_t)(g*64 + pb+0)*1024 + tid];
        r1 += Rpart[(size_t)(g*64 + pb+1)*1024 + tid];
        r2 += Rpart[(size_t)(g*64 + pb+2)*1024 + tid];
        r3 += Rpart[(size_t)(g*64 + pb+3)*1024 + tid];
    }
    float rs = (r0 + r1) + (r2 + r3);
    __syncthreads();

    if (tid < 32) {
        float s = 0.f;
        #pragma unroll
        for (int p = 0; p < 16; ++p) s += Spr[p][tid];
        S[tid] = s;
        M[tid] = s / (float)NTOT;
    }
    __syncthreads();

    const float invN = 1.0f/(float)NTOT;
    float v = rs - S[c]*S[d]*invN;
    if (c == d) v += EPSV;
    T[tid] = v;
    __syncthreads();

    if (tid == 0) {
        float tr = 0.f;
        for (int k = 0; k < 32; ++k) tr += T[k*33];
        sh_s = tr / 32.0f;
    }
    __syncthreads();
    float sc = sh_s;
    float invs = 1.0f / sc;

    Y[tid] = v * invs;
    Z[tid] = (c == d) ? 1.0f : 0.0f;
    __syncthreads();

    for (int it = 0; it < 8; ++it) {
        float s2 = 0.f;
        #pragma unroll
        for (int k = 0; k < 32; ++k) s2 = fmaf(Z[c*32 + k], Y[k*32 + d], s2);
        float a = ((c == d) ? 3.0f : 0.0f) - s2;
        __syncthreads();
        T[tid] = a;
        __syncthreads();
        float sy = 0.f, sz = 0.f;
        #pragma unroll
        for (int k = 0; k < 32; ++k) {
            sy = fmaf(Y[c*32 + k], T[k*32 + d], sy);
            sz = fmaf(T[c*32 + k], Z[k*32 + d], sz);
        }
        __syncthreads();
        Y[tid] = 0.5f*sy;
        Z[tid] = 0.5f*sz;
        __syncthreads();
    }

    float wfac = rsqrtf(sc);   // sigma^{-1/2} = Z / sqrt(s)
    wmT[(size_t)g*1024 + d*32 + c] = Z[tid]*wfac*weight[g*GS + c];  // transposed + weight-folded
    if (tid < 32) {
        float s2 = 0.f;
        #pragma unroll
        for (int k = 0; k < 32; ++k) s2 = fmaf(Z[tid*32 + k], M[k], s2);
        beta[g*GS + tid] = -s2*wfac*weight[g*GS + tid] + bias[g*GS + tid];
    }
}

// ---------------------------------------------------------------------------
// Kernel 3: whiten. out[c] = sum_d wmT[d][c] * x[d] + beta[c].
// R4: float2 per lane -> 512 B contiguous per wave-instruction (was 256 B
// scattered at 16 KB stride), half the load/store instructions. Accumulation
// order over d unchanged -> bit-identical results. acc[32] float2 = 64 VGPR.
// Dropped R3's nontemporal store (weakly negative: non-stats 226->234us).
// ---------------------------------------------------------------------------
__global__ __launch_bounds__(256) void dbn_whiten(const float* __restrict__ x,
                                                  const float* __restrict__ wmT,
                                                  const float* __restrict__ beta,
                                                  float* __restrict__ out) {
    int bx = blockIdx.x;            // 0..2047
    int gb = bx >> 3;               // 0..255
    int chunk = bx & 7;             // 512-sample chunk
    int b = gb >> 3, g = gb & 7;
    size_t base = ((size_t)(b*NFEAT + g*GS))*HW + chunk*512 + threadIdx.x*2;
    const float* wg = wmT + (size_t)g*1024;
    const float* bg = beta + (size_t)g*GS;

    float2 acc[32];
    #pragma unroll
    for (int c = 0; c < 32; ++c) { float bc = bg[c]; acc[c].x = bc; acc[c].y = bc; }

    #pragma unroll
    for (int d = 0; d < 32; ++d) {
        float2 vd = *(const float2*)(x + base + (size_t)d*HW);
        #pragma unroll
        for (int c = 0; c < 32; ++c) {
            float wv = wg[d*32 + c];
            acc[c].x = fmaf(wv, vd.x, acc[c].x);
            acc[c].y = fmaf(wv, vd.y, acc[c].y);
        }
    }

    #pragma unroll
    for (int c = 0; c < 32; ++c)
        *(float2*)(out + base + (size_t)c*HW) = acc[c];
}

extern "C" void kernel_launch(void* const* d_in, const int* in_sizes, int n_in,
                              void* d_out, int out_size, void* d_ws, size_t ws_size,
                              hipStream_t stream) {
    const float* x      = (const float*)d_in[0];
    const float* weight = (const float*)d_in[1];
    const float* bias   = (const float*)d_in[2];
    float* out = (float*)d_out;
    float* ws  = (float*)d_ws;

    float* Rpart = ws;
    float* Spart = ws + SPART_OFF;
    float* wmT   = ws + WMT_OFF;
    float* beta  = ws + BETA_OFF;

    dbn_stats <<<512, 1024, 0, stream>>>(x, Rpart, Spart);
    dbn_solver<<<NG, 1024, 0, stream>>>(Rpart, Spart, weight, bias, wmT, beta);
    dbn_whiten<<<2048, 256, 0, stream>>>(x, wmT, beta, out);
}